// Round 3
// baseline (564.393 us; speedup 1.0000x reference)
//
#include <hip/hip_runtime.h>
#include <cstdint>

// Column1: 512 independent (32x2048)@(2048x32) fp32 GEMMs + per-branch kWTA epilogue.
// R3: latency attack. R1/R2 both pinned at 144us / ~2.9 TB/s despite 2x occupancy
// delta -> latency-bound (Little's law: BW scaled with bytes-in-flight, not waves).
// Keep R2 structure (CHUNK=64, 32KB LDS, ~5 blocks/CU) but use a DEPTH=3 rolling
// register prefetch queue: 12 float4/thread outstanding (3x R2) during compute.

#define RFN 512
#define TN  32
#define KN  32
#define LN  2048
#define SPLIT 4
#define LSEG (LN / SPLIT)    // 512
#define CHUNK 64
#define NITER (LSEG / CHUNK) // 8
#define DEPTH 3              // chunks in flight beyond the one being computed

__global__ __launch_bounds__(256, 5) void column1_gemm(
    const float* __restrict__ rec,   // (T=32, C=1, RF=512, L=2048)
    const float* __restrict__ wgt,   // (RF=512, K=32, C=1, L=2048)
    float* __restrict__ wsout)       // (RF, SPLIT, 32*32) partial potentials
{
    __shared__ __align__(16) float lds[2 * 64 * CHUNK];  // 32768 B
    const int bs   = blockIdx.x;
    const int r    = bs >> 2;        // branch
    const int sseg = bs & 3;         // l-segment
    const int l0   = sseg * LSEG;
    const int tid  = threadIdx.x;
    const int lane = tid & 63;
    const int wv   = tid >> 6;       // wave 0..3: splits chunk's 16 quads 4-ways
    const int tg   = lane >> 3;      // 0..7 : owns t in {tg, tg+8, tg+16, tg+24}
    const int kg   = lane & 7;       // 0..7 : owns k in {kg, kg+8, kg+16, kg+24}

    // ---- staging: 4 float4/thread; rows r0+16s (0..31 rec-t, 32..63 wgt-k), quad c4
    const int c4 = tid & 15;         // quad within 64 floats
    const int r0 = tid >> 4;         // 0..15
    const float* gsrc[4];
    int ldoff[4];
#pragma unroll
    for (int s = 0; s < 4; ++s) {
        const int row = r0 + 16 * s;                // 0..63
        const float* g;
        if (row < 32) g = rec + ((size_t)(row * RFN + r)) * LN + l0 + (c4 << 2);
        else          g = wgt + ((size_t)(r * KN + (row - 32))) * LN + l0 + (c4 << 2);
        gsrc[s]  = g;
        // XOR swizzle: quad c4 stored at c4 ^ (row&15) -> conflict-free b128 reads, no pad
        ldoff[s] = row * CHUNK + ((c4 ^ (row & 15)) << 2);
    }

    // rolling prefetch queue: chunks 0..DEPTH-1 in flight before the loop
    float4 stage[DEPTH][4];
#pragma unroll
    for (int d = 0; d < DEPTH; ++d)
#pragma unroll
        for (int s = 0; s < 4; ++s) {
            stage[d][s] = *(const float4*)gsrc[s];
            gsrc[s] += CHUNK;
        }

    float acc[4][4];
#pragma unroll
    for (int jt = 0; jt < 4; ++jt)
#pragma unroll
        for (int jk = 0; jk < 4; ++jk) acc[jt][jk] = 0.0f;

    int qi = 0;  // queue slot holding the current chunk
    for (int it = 0; it < NITER; ++it) {
        float* buf = lds + (it & 1) * (64 * CHUNK);
#pragma unroll
        for (int s = 0; s < 4; ++s) *(float4*)(buf + ldoff[s]) = stage[qi][s];
        __syncthreads();                             // double-buffer: one barrier/chunk
        if (it + DEPTH < NITER) {
#pragma unroll
            for (int s = 0; s < 4; ++s) {
                stage[qi][s] = *(const float4*)gsrc[s];  // refill freed slot, chunk it+DEPTH
                gsrc[s] += CHUNK;
            }
        }
        const float* rs = buf;
        const float* wsh = buf + 32 * CHUNK;
#pragma unroll
        for (int q = 0; q < 4; ++q) {
            const int qg = (wv << 2) + q;            // this wave's l-quad (0..15)
            float4 a[4], b[4];
#pragma unroll
            for (int j = 0; j < 4; ++j) {
                const int row = tg + 8 * j;
                a[j] = *(const float4*)(rs + row * CHUNK + ((qg ^ (row & 15)) << 2));
            }
#pragma unroll
            for (int j = 0; j < 4; ++j) {
                const int row = kg + 8 * j;
                b[j] = *(const float4*)(wsh + row * CHUNK + ((qg ^ (row & 15)) << 2));
            }
#pragma unroll
            for (int jt = 0; jt < 4; ++jt)
#pragma unroll
                for (int jk = 0; jk < 4; ++jk) {
                    float v0 = fmaf(a[jt].x, b[jk].x, acc[jt][jk]);
                    v0 = fmaf(a[jt].y, b[jk].y, v0);
                    v0 = fmaf(a[jt].z, b[jk].z, v0);
                    acc[jt][jk] = fmaf(a[jt].w, b[jk].w, v0);
                }
        }
        qi = (qi + 1 == DEPTH) ? 0 : qi + 1;
    }

    // ---- cross-wave reduction into buffer-0 region (final compute read buffer 1 -> safe)
    float* red = lds;                                // 4 x 1024 floats = 16 KB
#pragma unroll
    for (int jt = 0; jt < 4; ++jt)
#pragma unroll
        for (int jk = 0; jk < 4; ++jk)
            red[(wv << 10) + (tg + 8 * jt) * 32 + (kg + 8 * jk)] = acc[jt][jk];
    __syncthreads();

    // partial potential (t,k) flat o = tid*4+e -> ws[(r*4+sseg)*1024 + o]
    const int o = tid << 2;
    float4 p0 = *(const float4*)(red + o);
    float4 p1 = *(const float4*)(red + 1024 + o);
    float4 p2 = *(const float4*)(red + 2048 + o);
    float4 p3 = *(const float4*)(red + 3072 + o);
    float4 pv;
    pv.x = p0.x + p1.x + p2.x + p3.x;
    pv.y = p0.y + p1.y + p2.y + p3.y;
    pv.z = p0.z + p1.z + p2.z + p3.z;
    pv.w = p0.w + p1.w + p2.w + p3.w;
    *(float4*)(wsout + (size_t)(r * SPLIT + sseg) * 1024 + o) = pv;
}

__global__ __launch_bounds__(256) void column1_epilogue(
    const float* __restrict__ wsin,  // (RF, SPLIT, 1024)
    float* __restrict__ out)         // (T=32, 1, K=32, RF=512)
{
    __shared__ float thr_s[32 * 33];
    __shared__ float nspk_s[32], vals_s[32], cand_s[32], tot_s[32], mask_s[32];
    const int r   = blockIdx.x;
    const int tid = threadIdx.x;
    const float* base = wsin + (size_t)r * (SPLIT * 1024);

    const int o = tid << 2;
    float4 p0 = *(const float4*)(base + o);
    float4 p1 = *(const float4*)(base + 1024 + o);
    float4 p2 = *(const float4*)(base + 2048 + o);
    float4 p3 = *(const float4*)(base + 3072 + o);
    float pv[4] = { p0.x + p1.x + p2.x + p3.x,
                    p0.y + p1.y + p2.y + p3.y,
                    p0.z + p1.z + p2.z + p3.z,
                    p0.w + p1.w + p2.w + p3.w };
#pragma unroll
    for (int e = 0; e < 4; ++e) {
        const int oo = o + e;
        const float th = (pv[e] > 20.0f) ? pv[e] : 0.0f;  // sf.fire: strictly greater
        thr_s[(oo >> 5) * 33 + (oo & 31)] = th;
    }
    __syncthreads();

    if (tid < 32) {
        const int k = tid;
        int ns = 0;
        for (int t = 0; t < 32; ++t) ns += (thr_s[t * 33 + k] > 0.0f) ? 1 : 0;
        int first = 32 - ns; if (first > 31) first = 31;   // clip(T - nspk, 0, T-1)
        const float vf = thr_s[first * 33 + k];
        nspk_s[k] = (float)ns;
        vals_s[k] = vf;
        cand_s[k] = (ns > 0) ? vf : 0.0f;                  // max_t spikes*vals per k
        mask_s[k] = 0.0f;
    }
    __syncthreads();

    if (tid == 0) {
        float vm = 0.0f;
        for (int k = 0; k < 32; ++k) vm = fmaxf(vm, cand_s[k]);
        const float v = vm * 32.0f;                        // trunc.max() * T
        for (int k = 0; k < 32; ++k) tot_s[k] = nspk_s[k] * (vals_s[k] + v);
        // top-4, ties -> lower index (matches lax.top_k); winner valid iff total != 0
        for (int sel = 0; sel < 4; ++sel) {
            int best = 0; float bv = -1.0f;
            for (int k = 0; k < 32; ++k) {
                const float tv = tot_s[k];
                if (tv > bv) { bv = tv; best = k; }
            }
            if (bv > 0.0f) mask_s[best] = 1.0f;
            tot_s[best] = -1.0f;
        }
    }
    __syncthreads();

#pragma unroll
    for (int e = 0; e < 4; ++e) {
        const int oo = o + e;
        const int t = oo >> 5, k = oo & 31;
        out[(size_t)t * (KN * RFN) + k * RFN + r] =
            (thr_s[t * 33 + k] > 0.0f && mask_s[k] > 0.0f) ? 1.0f : 0.0f;
    }
}

extern "C" void kernel_launch(void* const* d_in, const int* in_sizes, int n_in,
                              void* d_out, int out_size, void* d_ws, size_t ws_size,
                              hipStream_t stream) {
    const float* rec = (const float*)d_in[0];   // rec_field (32,1,512,2048)
    const float* wgt = (const float*)d_in[1];   // W         (512,32,1,2048)
    // d_in[2] = reward: unused by the forward output
    float* out = (float*)d_out;                 // (32,1,32,512)
    float* ws  = (float*)d_ws;                  // needs 512*4*1024*4 B = 8.4 MB
    column1_gemm<<<dim3(RFN * SPLIT), dim3(256), 0, stream>>>(rec, wgt, ws);
    column1_epilogue<<<dim3(RFN), dim3(256), 0, stream>>>(ws, out);
}

// Round 5
// 300.631 us; speedup vs baseline: 1.8774x; 1.8774x over previous
//
#include <hip/hip_runtime.h>
#include <cstdint>

// Column1: 512 independent (32x2048)@(2048x32) fp32 GEMMs + fused per-branch kWTA.
// R5 = R4 with native ext_vector float4 (HIP_vector_type rejected by
// __builtin_nontemporal_load). Non-temporal streaming loads: don't displace the
// harness-restore's dirty L3 lines (R2 showed 245 MB of useless writeback drain
// throttling reads to 2.9 TB/s). CHUNK=256 -> 1 KB contiguous per wave-instr,
// epilogue fused in-block (single dispatch, no ws traffic).

typedef float vf4 __attribute__((ext_vector_type(4)));

#define RFN 512
#define TN  32
#define KN  32
#define LN  2048
#define CHUNK 256
#define NITER (LN / CHUNK)   // 8

__global__ __launch_bounds__(256, 1) void column1_kernel(
    const float* __restrict__ rec,   // (T=32, C=1, RF=512, L=2048)
    const float* __restrict__ wgt,   // (RF=512, K=32, C=1, L=2048)
    float* __restrict__ out)         // (T=32, 1, K=32, RF=512)
{
    __shared__ __align__(16) float lds[2 * 64 * CHUNK];  // 128 KiB (of 160)
    const int r    = blockIdx.x;
    const int tid  = threadIdx.x;
    const int lane = tid & 63;
    const int wv   = tid >> 6;       // wave 0..3
    const int tg   = lane >> 3;      // 0..7 : owns t in {tg, tg+8, tg+16, tg+24}
    const int kg   = lane & 7;       // 0..7 : owns k in {kg, kg+8, kg+16, kg+24}

    // ---- staging: wave w loads rows w*16+s (s=0..15); 64 lanes cover one full
    // 1 KB row per instruction (16 B/lane) -> long contiguous HBM runs.
    // waves 0,1 -> rec rows 0..31 (t), waves 2,3 -> wgt rows 32..63 (k).
    const int row0 = wv << 4;                        // first row of this wave
    const float* gbase;
    size_t rstride;                                  // row stride in floats
    if (wv < 2) { gbase = rec + ((size_t)(row0 * RFN + r)) * LN;        rstride = (size_t)RFN * LN; }
    else        { gbase = wgt + ((size_t)(r * KN + (row0 - 32))) * LN;  rstride = LN; }
    gbase += (lane << 2);

    // LDS offsets: element quad q of row stored at row*256 + ((q ^ (row&15))*4)
    int ldoff[16];
#pragma unroll
    for (int s = 0; s < 16; ++s) {
        const int row = row0 + s;
        ldoff[s] = row * CHUNK + ((lane ^ (row & 15)) << 2);
    }

    vf4 stage[16];                                   // static indices only!
#pragma unroll
    for (int s = 0; s < 16; ++s)
        stage[s] = __builtin_nontemporal_load((const vf4*)(gbase + s * rstride));

    float acc[4][4];
#pragma unroll
    for (int jt = 0; jt < 4; ++jt)
#pragma unroll
        for (int jk = 0; jk < 4; ++jk) acc[jt][jk] = 0.0f;

    for (int it = 0; it < NITER; ++it) {
        float* buf = lds + (it & 1) * (64 * CHUNK);
#pragma unroll
        for (int s = 0; s < 16; ++s) *(vf4*)(buf + ldoff[s]) = stage[s];
        __syncthreads();
        if (it + 1 < NITER) {
            const float* g = gbase + (size_t)(it + 1) * CHUNK;
#pragma unroll
            for (int s = 0; s < 16; ++s)
                stage[s] = __builtin_nontemporal_load((const vf4*)(g + s * rstride));
        }
        const float* rs  = buf;
#pragma unroll
        for (int q = 0; q < 16; ++q) {
            const int qg = (wv << 4) + q;            // this wave's l-quad (0..63)
            vf4 a[4], b[4];
#pragma unroll
            for (int j = 0; j < 4; ++j) {
                const int row = tg + 8 * j;
                a[j] = *(const vf4*)(rs + row * CHUNK + ((qg ^ (row & 15)) << 2));
            }
#pragma unroll
            for (int j = 0; j < 4; ++j) {
                const int row = 32 + kg + 8 * j;
                b[j] = *(const vf4*)(rs + row * CHUNK + ((qg ^ (row & 15)) << 2));
            }
#pragma unroll
            for (int jt = 0; jt < 4; ++jt)
#pragma unroll
                for (int jk = 0; jk < 4; ++jk) {
                    float v0 = fmaf(a[jt].x, b[jk].x, acc[jt][jk]);
                    v0 = fmaf(a[jt].y, b[jk].y, v0);
                    v0 = fmaf(a[jt].z, b[jk].z, v0);
                    acc[jt][jk] = fmaf(a[jt].w, b[jk].w, v0);
                }
        }
    }

    // ---- cross-wave reduction into buffer-0 region (final compute reads buffer 1)
    float* red = lds;                                // 4 x 1024 floats
#pragma unroll
    for (int jt = 0; jt < 4; ++jt)
#pragma unroll
        for (int jk = 0; jk < 4; ++jk)
            red[(wv << 10) + (tg + 8 * jt) * 32 + (kg + 8 * jk)] = acc[jt][jk];
    __syncthreads();

    float* thr_s = lds + 4096;                       // 32 x 33 (padded)
#pragma unroll
    for (int e = 0; e < 4; ++e) {
        const int o = (tid << 2) + e;                // flat (t,k), 4 per thread
        float pv = red[o] + red[1024 + o] + red[2048 + o] + red[3072 + o];
        float th = (pv > 20.0f) ? pv : 0.0f;         // sf.fire: strictly greater
        thr_s[(o >> 5) * 33 + (o & 31)] = th;
    }
    __syncthreads();

    float* nspk_s = lds + 4096 + 1056;
    float* vals_s = nspk_s + 32;
    float* cand_s = vals_s + 32;
    float* tot_s  = cand_s + 32;
    float* mask_s = tot_s + 32;

    if (tid < 32) {
        const int k = tid;
        int ns = 0;
        for (int t = 0; t < 32; ++t) ns += (thr_s[t * 33 + k] > 0.0f) ? 1 : 0;
        int first = 32 - ns; if (first > 31) first = 31;   // clip(T - nspk, 0, T-1)
        const float vf = thr_s[first * 33 + k];
        nspk_s[k] = (float)ns;
        vals_s[k] = vf;
        cand_s[k] = (ns > 0) ? vf : 0.0f;            // max_t spikes*vals per k
        mask_s[k] = 0.0f;
    }
    __syncthreads();

    if (tid == 0) {
        float vm = 0.0f;
        for (int k = 0; k < 32; ++k) vm = fmaxf(vm, cand_s[k]);
        const float v = vm * 32.0f;                  // trunc.max() * T
        for (int k = 0; k < 32; ++k) tot_s[k] = nspk_s[k] * (vals_s[k] + v);
        // top-4, ties -> lower index (matches lax.top_k); winner valid iff total != 0
        for (int sel = 0; sel < 4; ++sel) {
            int best = 0; float bv = -1.0f;
            for (int k = 0; k < 32; ++k) {
                const float tv = tot_s[k];
                if (tv > bv) { bv = tv; best = k; }
            }
            if (bv > 0.0f) mask_s[best] = 1.0f;
            tot_s[best] = -1.0f;
        }
    }
    __syncthreads();

    // out[t,0,k,r] = spike[t,k] & mask[k]
#pragma unroll
    for (int e = 0; e < 4; ++e) {
        const int o = (tid << 2) + e;
        const int t = o >> 5, k = o & 31;
        const float v = (thr_s[t * 33 + k] > 0.0f && mask_s[k] > 0.0f) ? 1.0f : 0.0f;
        __builtin_nontemporal_store(v, out + (size_t)t * (KN * RFN) + k * RFN + r);
    }
}

extern "C" void kernel_launch(void* const* d_in, const int* in_sizes, int n_in,
                              void* d_out, int out_size, void* d_ws, size_t ws_size,
                              hipStream_t stream) {
    const float* rec = (const float*)d_in[0];   // rec_field (32,1,512,2048)
    const float* wgt = (const float*)d_in[1];   // W         (512,32,1,2048)
    // d_in[2] = reward: unused by the forward output
    float* out = (float*)d_out;                 // (32,1,32,512)
    column1_kernel<<<dim3(RFN), dim3(256), 0, stream>>>(rec, wgt, out);
}

// Round 6
// 294.028 us; speedup vs baseline: 1.9195x; 1.0225x over previous
//
#include <hip/hip_runtime.h>
#include <cstdint>

// Column1: 512 independent (32x2048)@(2048x32) fp32 GEMMs + per-branch kWTA epilogue.
// R6 = R2's verified structure (CHUNK=64, 32KB LDS, split-4, 2048 blocks, ~5
// blocks/CU) + R5's proven non-temporal loads (killed the 245 MB dirty-L3
// writeback storm: WRITE 254->32 MB). R5 showed the remaining limiter is
// overlap: 1 block/CU serialized the per-chunk barrier drains with the
// LDS-pipe floor (~41 us/CU of logical ds_read traffic). 5 resident blocks
// let fetch, LDS, and VALU phases of different blocks overlap.

typedef float vf4 __attribute__((ext_vector_type(4)));

#define RFN 512
#define TN  32
#define KN  32
#define LN  2048
#define SPLIT 4
#define LSEG (LN / SPLIT)    // 512
#define CHUNK 64
#define NITER (LSEG / CHUNK) // 8

__global__ __launch_bounds__(256, 5) void column1_gemm(
    const float* __restrict__ rec,   // (T=32, C=1, RF=512, L=2048)
    const float* __restrict__ wgt,   // (RF=512, K=32, C=1, L=2048)
    float* __restrict__ wsout)       // (RF, SPLIT, 32*32) partial potentials
{
    __shared__ __align__(16) float lds[2 * 64 * CHUNK];  // 32768 B
    const int bs   = blockIdx.x;
    const int r    = bs >> 2;        // branch
    const int sseg = bs & 3;         // l-segment
    const int l0   = sseg * LSEG;
    const int tid  = threadIdx.x;
    const int lane = tid & 63;
    const int wv   = tid >> 6;       // wave 0..3: splits chunk's 16 quads 4-ways
    const int tg   = lane >> 3;      // 0..7 : owns t in {tg, tg+8, tg+16, tg+24}
    const int kg   = lane & 7;       // 0..7 : owns k in {kg, kg+8, kg+16, kg+24}

    // ---- staging: 4 vf4/thread; rows r0+16s (0..31 rec-t, 32..63 wgt-k), quad c4
    const int c4 = tid & 15;         // quad within 64 floats
    const int r0 = tid >> 4;         // 0..15
    const float* gsrc[4];
    int ldoff[4];
#pragma unroll
    for (int s = 0; s < 4; ++s) {
        const int row = r0 + 16 * s;                // 0..63
        const float* g;
        if (row < 32) g = rec + ((size_t)(row * RFN + r)) * LN + l0 + (c4 << 2);
        else          g = wgt + ((size_t)(r * KN + (row - 32))) * LN + l0 + (c4 << 2);
        gsrc[s]  = g;
        // XOR swizzle: quad c4 stored at c4 ^ (row&15) -> conflict-free b128 reads, no pad
        ldoff[s] = row * CHUNK + ((c4 ^ (row & 15)) << 2);
    }

    vf4 stage[4];
#pragma unroll
    for (int s = 0; s < 4; ++s)
        stage[s] = __builtin_nontemporal_load((const vf4*)gsrc[s]);

    float acc[4][4];
#pragma unroll
    for (int jt = 0; jt < 4; ++jt)
#pragma unroll
        for (int jk = 0; jk < 4; ++jk) acc[jt][jk] = 0.0f;

    for (int it = 0; it < NITER; ++it) {
        float* buf = lds + (it & 1) * (64 * CHUNK);
#pragma unroll
        for (int s = 0; s < 4; ++s) *(vf4*)(buf + ldoff[s]) = stage[s];
        __syncthreads();                             // double-buffer: one barrier/chunk
        if (it + 1 < NITER) {
#pragma unroll
            for (int s = 0; s < 4; ++s) {
                gsrc[s] += CHUNK;
                stage[s] = __builtin_nontemporal_load((const vf4*)gsrc[s]);
            }
        }
        const float* rs  = buf;
        const float* wsh = buf + 32 * CHUNK;
#pragma unroll
        for (int q = 0; q < 4; ++q) {
            const int qg = (wv << 2) + q;            // this wave's l-quad (0..15)
            vf4 a[4], b[4];
#pragma unroll
            for (int j = 0; j < 4; ++j) {
                const int row = tg + 8 * j;
                a[j] = *(const vf4*)(rs + row * CHUNK + ((qg ^ (row & 15)) << 2));
            }
#pragma unroll
            for (int j = 0; j < 4; ++j) {
                const int row = kg + 8 * j;
                b[j] = *(const vf4*)(wsh + row * CHUNK + ((qg ^ (row & 15)) << 2));
            }
#pragma unroll
            for (int jt = 0; jt < 4; ++jt)
#pragma unroll
                for (int jk = 0; jk < 4; ++jk) {
                    float v0 = fmaf(a[jt].x, b[jk].x, acc[jt][jk]);
                    v0 = fmaf(a[jt].y, b[jk].y, v0);
                    v0 = fmaf(a[jt].z, b[jk].z, v0);
                    acc[jt][jk] = fmaf(a[jt].w, b[jk].w, v0);
                }
        }
    }

    // ---- cross-wave reduction into buffer-0 region (final compute read buffer 1 -> safe)
    float* red = lds;                                // 4 x 1024 floats = 16 KB
#pragma unroll
    for (int jt = 0; jt < 4; ++jt)
#pragma unroll
        for (int jk = 0; jk < 4; ++jk)
            red[(wv << 10) + (tg + 8 * jt) * 32 + (kg + 8 * jk)] = acc[jt][jk];
    __syncthreads();

    // partial potential (t,k) flat o = tid*4+e -> ws[(r*4+sseg)*1024 + o]
    const int o = tid << 2;
    vf4 p0 = *(const vf4*)(red + o);
    vf4 p1 = *(const vf4*)(red + 1024 + o);
    vf4 p2 = *(const vf4*)(red + 2048 + o);
    vf4 p3 = *(const vf4*)(red + 3072 + o);
    vf4 pv = p0 + p1 + p2 + p3;
    *(vf4*)(wsout + (size_t)(r * SPLIT + sseg) * 1024 + o) = pv;   // regular store: L3-served by epilogue
}

__global__ __launch_bounds__(256) void column1_epilogue(
    const float* __restrict__ wsin,  // (RF, SPLIT, 1024)
    float* __restrict__ out)         // (T=32, 1, K=32, RF=512)
{
    __shared__ float thr_s[32 * 33];
    __shared__ float nspk_s[32], vals_s[32], cand_s[32], tot_s[32], mask_s[32];
    const int r   = blockIdx.x;
    const int tid = threadIdx.x;
    const float* base = wsin + (size_t)r * (SPLIT * 1024);

    const int o = tid << 2;
    vf4 p0 = *(const vf4*)(base + o);
    vf4 p1 = *(const vf4*)(base + 1024 + o);
    vf4 p2 = *(const vf4*)(base + 2048 + o);
    vf4 p3 = *(const vf4*)(base + 3072 + o);
    vf4 ps = p0 + p1 + p2 + p3;
    float pv[4] = { ps.x, ps.y, ps.z, ps.w };
#pragma unroll
    for (int e = 0; e < 4; ++e) {
        const int oo = o + e;
        const float th = (pv[e] > 20.0f) ? pv[e] : 0.0f;  // sf.fire: strictly greater
        thr_s[(oo >> 5) * 33 + (oo & 31)] = th;
    }
    __syncthreads();

    if (tid < 32) {
        const int k = tid;
        int ns = 0;
        for (int t = 0; t < 32; ++t) ns += (thr_s[t * 33 + k] > 0.0f) ? 1 : 0;
        int first = 32 - ns; if (first > 31) first = 31;   // clip(T - nspk, 0, T-1)
        const float vf = thr_s[first * 33 + k];
        nspk_s[k] = (float)ns;
        vals_s[k] = vf;
        cand_s[k] = (ns > 0) ? vf : 0.0f;                  // max_t spikes*vals per k
        mask_s[k] = 0.0f;
    }
    __syncthreads();

    if (tid == 0) {
        float vm = 0.0f;
        for (int k = 0; k < 32; ++k) vm = fmaxf(vm, cand_s[k]);
        const float v = vm * 32.0f;                        // trunc.max() * T
        for (int k = 0; k < 32; ++k) tot_s[k] = nspk_s[k] * (vals_s[k] + v);
        // top-4, ties -> lower index (matches lax.top_k); winner valid iff total != 0
        for (int sel = 0; sel < 4; ++sel) {
            int best = 0; float bv = -1.0f;
            for (int k = 0; k < 32; ++k) {
                const float tv = tot_s[k];
                if (tv > bv) { bv = tv; best = k; }
            }
            if (bv > 0.0f) mask_s[best] = 1.0f;
            tot_s[best] = -1.0f;
        }
    }
    __syncthreads();

#pragma unroll
    for (int e = 0; e < 4; ++e) {
        const int oo = o + e;
        const int t = oo >> 5, k = oo & 31;
        const float v = (thr_s[t * 33 + k] > 0.0f && mask_s[k] > 0.0f) ? 1.0f : 0.0f;
        __builtin_nontemporal_store(v, out + (size_t)t * (KN * RFN) + k * RFN + r);
    }
}

extern "C" void kernel_launch(void* const* d_in, const int* in_sizes, int n_in,
                              void* d_out, int out_size, void* d_ws, size_t ws_size,
                              hipStream_t stream) {
    const float* rec = (const float*)d_in[0];   // rec_field (32,1,512,2048)
    const float* wgt = (const float*)d_in[1];   // W         (512,32,1,2048)
    // d_in[2] = reward: unused by the forward output
    float* out = (float*)d_out;                 // (32,1,32,512)
    float* ws  = (float*)d_ws;                  // needs 512*4*1024*4 B = 8.4 MB
    column1_gemm<<<dim3(RFN * SPLIT), dim3(256), 0, stream>>>(rec, wgt, ws);
    column1_epilogue<<<dim3(RFN), dim3(256), 0, stream>>>(ws, out);
}